// Round 7
// baseline (238.227 us; speedup 1.0000x reference)
//
#include <hip/hip_runtime.h>

// Problem constants (B,C,H,W fixed by setup_inputs)
#define BB  16
#define HH  384
#define WW  1280
#define TPB 256   // threads per block, along W (1280 = 5*256)
#define ROWS 16   // rows per block strip (384 = 24*16): grid 1920 = 7.5 blocks/CU
                  // = 30 waves/CU co-resident (VGPR 56 allows 32). R5->R6: the
                  // grid was the only residency cap left; double it.
#define NSLOT 64  // accumulator slots, one 64B line each

// Raw 3-tap row fetch with column zero-padding.
__device__ __forceinline__ void load_row3(const float* __restrict__ plane, int i, int j,
                                          float& a, float& b, float& c) {
    const float* row = plane + (size_t)i * WW;
    a = (j > 0)      ? row[j - 1] : 0.f;
    b = row[j];
    c = (j < WW - 1) ? row[j + 1] : 0.f;
}

__global__ __launch_bounds__(TPB)   // no min-waves arg: R3 showed it forces spills
void NormalLoss_44478681317469_main(const float* __restrict__ pred,
                                    const float* __restrict__ gt,
                                    const float* __restrict__ mask,
                                    double* __restrict__ acc)
{
    const int j  = blockIdx.x * TPB + threadIdx.x;   // column
    const int r0 = blockIdx.y * ROWS;                // strip start row
    const int b  = blockIdx.z;

    const float* pl[6];
#pragma unroll
    for (int c = 0; c < 3; ++c) {
        pl[c]     = pred + (size_t)(b * 3 + c) * HH * WW;
        pl[3 + c] = gt   + (size_t)(b * 3 + c) * HH * WW;
    }
    const float* mpl = mask + (size_t)b * HH * WW;

    // Rolling D (horiz diff) / T (horiz sum) state for rows i-1, i.
    float Dm1[6], D0[6], Tm1[6], T0[6];
    // Raw lookahead: row i+1 currently in flight from memory.
    float Ra[6], Rb[6], Rc[6];

#pragma unroll
    for (int c = 0; c < 6; ++c) {
        if (r0 > 0) {   // uniform per block
            float a, bb, cc; load_row3(pl[c], r0 - 1, j, a, bb, cc);
            Dm1[c] = cc - a; Tm1[c] = a + bb + cc;
        } else { Dm1[c] = 0.f; Tm1[c] = 0.f; }   // zero padding above row 0
        {
            float a, bb, cc; load_row3(pl[c], r0, j, a, bb, cc);
            D0[c] = cc - a; T0[c] = a + bb + cc;
        }
    }

    // Issue loads for row r0+1 (consumed at top of first iteration).
#pragma unroll
    for (int c = 0; c < 6; ++c)
        load_row3(pl[c], r0 + 1, j, Ra[c], Rb[c], Rc[c]);   // r0+1 <= 369 < HH
    float mrow = mpl[(size_t)r0 * WW + j];

    float lsum = 0.f, msum = 0.f;

#pragma unroll 2    // rolling loop: keeps VGPR ~56 (R5), allows rename-by-2
    for (int k = 0; k < ROWS; ++k) {
        const int i = r0 + k;

        // Consume lookahead -> D/T for row i+1 (loads issued one iter ago).
        float Dp1[6], Tp1[6];
#pragma unroll
        for (int c = 0; c < 6; ++c) {
            Dp1[c] = Rc[c] - Ra[c];
            Tp1[c] = Ra[c] + Rb[c] + Rc[c];
        }
        float m = mrow;

        // Prefetch row i+2 (+ next mask row) NOW, overlapping the math below.
        if (i + 2 < HH) {   // uniform per block
#pragma unroll
            for (int c = 0; c < 6; ++c) load_row3(pl[c], i + 2, j, Ra[c], Rb[c], Rc[c]);
        } else {
#pragma unroll
            for (int c = 0; c < 6; ++c) { Ra[c] = 0.f; Rb[c] = 0.f; Rc[c] = 0.f; }
        }
        if (k + 1 < ROWS) mrow = mpl[(size_t)(i + 1) * WW + j];

        // Gradients (global factor 3 dropped; cancels in normalization)
        float gx[6], gy[6];
#pragma unroll
        for (int c = 0; c < 6; ++c) {
            gx[c] = Dm1[c] + D0[c] + Dp1[c];
            gy[c] = Tp1[c] - Tm1[c];
        }

        // normal = cross(gx_vec, gy_vec), per reference component expressions
        float n0p = gx[1] * gy[2] - gx[2] * gy[1];
        float n1p = gx[2] * gy[0] - gx[0] * gy[2];
        float n2p = gx[0] * gy[1] - gx[1] * gy[0];
        float n0g = gx[4] * gy[5] - gx[5] * gy[4];
        float n1g = gx[5] * gy[3] - gx[3] * gy[5];
        float n2g = gx[3] * gy[4] - gx[4] * gy[3];

        float sp = n0p * n0p + n1p * n1p + n2p * n2p;
        float sg = n0g * n0g + n1g * n1g + n2g * n2g;
        // ref: normal/(sqrt(s)+1e-10); rsq rel-err ~2e-6; guard s~0 -> 0
        float ip = (sp > 1e-20f) ? __builtin_amdgcn_rsqf(sp) : 0.f;
        float ig = (sg > 1e-20f) ? __builtin_amdgcn_rsqf(sg) : 0.f;

        float d0 = fabsf(n0p * ip - n0g * ig);
        float d1 = fabsf(n1p * ip - n1g * ig);
        float d2 = fabsf(n2p * ip - n2g * ig);

        lsum += m * (d0 + d1 + d2);
        msum += m;

        // Rotate rolling state (plain copies; unroll-2 lets compiler rename).
#pragma unroll
        for (int c = 0; c < 6; ++c) {
            Dm1[c] = D0[c]; D0[c] = Dp1[c];
            Tm1[c] = T0[c]; T0[c] = Tp1[c];
        }
    }

    // Wave(64) shuffle reduction, cross-wave via LDS, one atomic pair per block.
#pragma unroll
    for (int off = 32; off > 0; off >>= 1) {
        lsum += __shfl_down(lsum, off, 64);
        msum += __shfl_down(msum, off, 64);
    }
    __shared__ float sL[TPB / 64], sM[TPB / 64];
    const int lane = threadIdx.x & 63;
    const int wid  = threadIdx.x >> 6;
    if (lane == 0) { sL[wid] = lsum; sM[wid] = msum; }
    __syncthreads();
    if (threadIdx.x == 0) {
        float L = 0.f, M = 0.f;
#pragma unroll
        for (int w = 0; w < TPB / 64; ++w) { L += sL[w]; M += sM[w]; }
        const int linear = (blockIdx.z * gridDim.y + blockIdx.y) * gridDim.x + blockIdx.x;
        double* slot = acc + (size_t)(linear & (NSLOT - 1)) * 8;  // 64B stride
        atomicAdd(&slot[0], (double)L);
        atomicAdd(&slot[1], (double)M);
    }
}

__global__ void NormalLoss_44478681317469_final(const double* __restrict__ acc,
                                                float* __restrict__ out)
{
    const int t = threadIdx.x;   // 64 threads, one per slot
    double L = acc[(size_t)t * 8 + 0];
    double M = acc[(size_t)t * 8 + 1];
#pragma unroll
    for (int off = 32; off > 0; off >>= 1) {
        L += __shfl_down(L, off, 64);
        M += __shfl_down(M, off, 64);
    }
    if (t == 0) out[0] = (float)(L / M);
}

extern "C" void kernel_launch(void* const* d_in, const int* in_sizes, int n_in,
                              void* d_out, int out_size, void* d_ws, size_t ws_size,
                              hipStream_t stream)
{
    const float* pred = (const float*)d_in[0];
    const float* gt   = (const float*)d_in[1];
    const float* mask = (const float*)d_in[2];
    double* acc = (double*)d_ws;

    // d_ws is poisoned 0xAA before every timed launch — zero the slot array.
    hipMemsetAsync(acc, 0, NSLOT * 8 * sizeof(double), stream);

    dim3 grid(WW / TPB, HH / ROWS, BB);   // 5 x 24 x 16 = 1920 co-resident blocks
    NormalLoss_44478681317469_main<<<grid, dim3(TPB), 0, stream>>>(pred, gt, mask, acc);
    NormalLoss_44478681317469_final<<<1, 64, 0, stream>>>(acc, (float*)d_out);
}